// Round 2
// baseline (369.321 us; speedup 1.0000x reference)
//
#include <hip/hip_runtime.h>
#include <stdint.h>

#define BB 4
#define NN 2048
#define FIN 256
#define FOUT 128
#define NH 4
#define NEG_SLOPE 0.2f

// ---------------------------------------------------------------------------
// K1: Wh[b,n,o] = sum_f h[b,n,f]*W_w[o,f] + W_b[o]   (fp32)
//     eL[b,h,n] = dot(Wh row, attn_w[h,:128]); eR = dot(Wh row, attn_w[h,128:])
// block = 128 threads (one per o), 8 rows per block.
// ---------------------------------------------------------------------------
#define K1_ROWS 8
__global__ __launch_bounds__(128) void k1_wh(
    const float* __restrict__ h, const float* __restrict__ Ww,
    const float* __restrict__ Wb, const float* __restrict__ attw,
    float* __restrict__ Wh, float* __restrict__ eL, float* __restrict__ eR) {
    __shared__ float hs[K1_ROWS][FIN];        // 8 KB
    __shared__ float whs[K1_ROWS][FOUT + 4];
    int t = threadIdx.x;
    int b = blockIdx.x >> 8;        // 256 tiles per batch (1024 blocks total)
    int tile = blockIdx.x & 255;
    int n0 = tile * K1_ROWS;
    const float* hb = h + ((size_t)(b * NN + n0)) * FIN;
    #pragma unroll
    for (int k = 0; k < 4; ++k) {               // 128 thr * 4 * float4 = 2048 floats
        int flat = (t + 128 * k) * 4;
        int r = flat >> 8, f = flat & 255;
        *(float4*)&hs[r][f] = *(const float4*)(hb + flat);
    }
    __syncthreads();
    int o = t;
    float bias = Wb[o];
    float acc[K1_ROWS];
    #pragma unroll
    for (int r = 0; r < K1_ROWS; ++r) acc[r] = bias;
    const float* wrow = Ww + (size_t)o * FIN;
    for (int fc = 0; fc < FIN / 4; ++fc) {
        float4 wq = *(const float4*)(wrow + fc * 4);
        #pragma unroll
        for (int r = 0; r < K1_ROWS; ++r) {
            float4 hv = *(const float4*)(&hs[r][fc * 4]);
            acc[r] = fmaf(hv.x, wq.x, acc[r]);
            acc[r] = fmaf(hv.y, wq.y, acc[r]);
            acc[r] = fmaf(hv.z, wq.z, acc[r]);
            acc[r] = fmaf(hv.w, wq.w, acc[r]);
        }
    }
    #pragma unroll
    for (int r = 0; r < K1_ROWS; ++r) {
        Wh[((size_t)(b * NN + n0 + r)) * FOUT + o] = acc[r];
        whs[r][o] = acc[r];
    }
    __syncthreads();
    if (t < 64) {
        int r = t >> 3, d = t & 7;
        int hh = d & 3, side = d >> 2;
        const float* arow = attw + hh * (2 * FOUT) + side * FOUT;
        float s = 0.f;
        for (int oo = 0; oo < FOUT; ++oo) s = fmaf(whs[r][oo], arow[oo], s);
        float* dst = side ? eR : eL;
        dst[(b * NH + hh) * NN + (n0 + r)] = s;
    }
}

// ---------------------------------------------------------------------------
// K_pack: adj (N x N int32) -> bitmask (N x 32 u64)
// ---------------------------------------------------------------------------
__global__ __launch_bounds__(256) void k_pack(const int* __restrict__ adj,
                                              unsigned long long* __restrict__ mask) {
    int row = blockIdx.x;
    int wave = threadIdx.x >> 6, lane = threadIdx.x & 63;
    #pragma unroll
    for (int it = 0; it < 8; ++it) {
        int w = it * 4 + wave;
        int j = w * 64 + lane;
        unsigned long long m = __ballot(adj[(size_t)row * NN + j] != 0);
        if (lane == 0) mask[row * 32 + w] = m;
    }
}

// ---------------------------------------------------------------------------
// K2a: per (b,h,i): m = masked max of leaky(el+er); s = sum exp(e-m);
//      inv = 1/(4*s) (0 if empty). 256 threads per (b,i).
// ---------------------------------------------------------------------------
__global__ __launch_bounds__(256) void k2a_stats(
    const int* __restrict__ adj, const float* __restrict__ eL,
    const float* __restrict__ eR, float* __restrict__ mOut, float* __restrict__ invOut) {
    __shared__ float red[4];
    int t = threadIdx.x;
    int b = blockIdx.x >> 11;
    int i = blockIdx.x & (NN - 1);
    int bits[8];
    #pragma unroll
    for (int jt = 0; jt < 8; ++jt) bits[jt] = adj[(size_t)i * NN + jt * 256 + t];
    for (int hh = 0; hh < NH; ++hh) {
        float el = eL[(b * NH + hh) * NN + i];
        const float* err = eR + (size_t)(b * NH + hh) * NN;
        float ee[8];
        float m = -INFINITY;
        #pragma unroll
        for (int jt = 0; jt < 8; ++jt) {
            float e = el + err[jt * 256 + t];
            e = e > 0.f ? e : NEG_SLOPE * e;
            ee[jt] = e;
            if (bits[jt]) m = fmaxf(m, e);
        }
        #pragma unroll
        for (int off = 32; off; off >>= 1) m = fmaxf(m, __shfl_xor(m, off));
        if ((t & 63) == 0) red[t >> 6] = m;
        __syncthreads();
        m = fmaxf(fmaxf(red[0], red[1]), fmaxf(red[2], red[3]));
        __syncthreads();
        float s = 0.f;
        #pragma unroll
        for (int jt = 0; jt < 8; ++jt) {
            float p = __expf(ee[jt] - m);
            s += bits[jt] ? p : 0.f;
        }
        #pragma unroll
        for (int off = 32; off; off >>= 1) s += __shfl_xor(s, off);
        if ((t & 63) == 0) red[t >> 6] = s;
        __syncthreads();
        s = red[0] + red[1] + red[2] + red[3];
        if (t == 0) {
            mOut[(b * NH + hh) * NN + i] = m;
            invOut[(b * NH + hh) * NN + i] = (s > 0.f) ? 1.f / (4.f * s) : 0.f;
        }
        __syncthreads();
    }
}

// ---------------------------------------------------------------------------
// K2b: out[b,i,o] = relu( sum_j w[i,j] * Wh[b,j,o] )
//      w[i,j] = adj_ij ? sum_h exp(leaky(el+er)-m_h)*inv_h : 0
// block = 256 threads per (b, i-tile of 16); j tiled by 256 through LDS.
// ---------------------------------------------------------------------------
#define TI 16
__global__ __launch_bounds__(256) void k2b_agg(
    const float* __restrict__ Wh, const float* __restrict__ eL,
    const float* __restrict__ eR, const float* __restrict__ mIn,
    const float* __restrict__ invIn, const unsigned long long* __restrict__ mask,
    float* __restrict__ out) {
    __shared__ float wt[TI][257];
    __shared__ float els[NH][TI], ms[NH][TI], invs[NH][TI];
    __shared__ unsigned long long mw[TI][4];
    int t = threadIdx.x;
    int b = blockIdx.y;
    int i0 = blockIdx.x * TI;
    if (t < NH * TI) {
        int hh = t >> 4, il = t & 15;
        els[hh][il]  = eL[(b * NH + hh) * NN + i0 + il];
        ms[hh][il]   = mIn[(b * NH + hh) * NN + i0 + il];
        invs[hh][il] = invIn[(b * NH + hh) * NN + i0 + il];
    }
    int il = t & 15, og = t >> 4;
    float acc[8];
    #pragma unroll
    for (int k = 0; k < 8; ++k) acc[k] = 0.f;
    const float* whb = Wh + (size_t)b * NN * FOUT + og * 8;

    for (int jt = 0; jt < 8; ++jt) {
        int j0 = jt * 256;
        if (t < 64) {
            int r = t >> 2, wsel = t & 3;
            mw[r][wsel] = mask[(size_t)(i0 + r) * 32 + jt * 4 + wsel];
        }
        __syncthreads();
        {   // w-gen: thread == jl
            int jl = t;
            float er0 = eR[(b * NH + 0) * NN + j0 + jl];
            float er1 = eR[(b * NH + 1) * NN + j0 + jl];
            float er2 = eR[(b * NH + 2) * NN + j0 + jl];
            float er3 = eR[(b * NH + 3) * NN + j0 + jl];
            unsigned int sh = jl & 63;
            int wsel = jl >> 6;
            #pragma unroll 4
            for (int r = 0; r < TI; ++r) {
                unsigned long long wd = mw[r][wsel];
                int bit = (int)((wd >> sh) & 1ull);
                float e0 = els[0][r] + er0; e0 = e0 > 0.f ? e0 : NEG_SLOPE * e0;
                float e1 = els[1][r] + er1; e1 = e1 > 0.f ? e1 : NEG_SLOPE * e1;
                float e2 = els[2][r] + er2; e2 = e2 > 0.f ? e2 : NEG_SLOPE * e2;
                float e3 = els[3][r] + er3; e3 = e3 > 0.f ? e3 : NEG_SLOPE * e3;
                float p = __expf(e0 - ms[0][r]) * invs[0][r];
                p = fmaf(__expf(e1 - ms[1][r]), invs[1][r], p);
                p = fmaf(__expf(e2 - ms[2][r]), invs[2][r], p);
                p = fmaf(__expf(e3 - ms[3][r]), invs[3][r], p);
                wt[r][jl] = bit ? p : 0.f;
            }
        }
        __syncthreads();
        const float* wjb = whb + (size_t)j0 * FOUT;
        #pragma unroll 4
        for (int jl = 0; jl < 256; ++jl) {
            float wv = wt[il][jl];
            const float* p = wjb + (size_t)jl * FOUT;
            float4 v0 = *(const float4*)(p);
            float4 v1 = *(const float4*)(p + 4);
            acc[0] = fmaf(wv, v0.x, acc[0]);
            acc[1] = fmaf(wv, v0.y, acc[1]);
            acc[2] = fmaf(wv, v0.z, acc[2]);
            acc[3] = fmaf(wv, v0.w, acc[3]);
            acc[4] = fmaf(wv, v1.x, acc[4]);
            acc[5] = fmaf(wv, v1.y, acc[5]);
            acc[6] = fmaf(wv, v1.z, acc[6]);
            acc[7] = fmaf(wv, v1.w, acc[7]);
        }
    }
    float* op = out + ((size_t)(b * NN + i0 + il)) * FOUT + og * 8;
    float4 s0, s1;
    s0.x = fmaxf(acc[0], 0.f); s0.y = fmaxf(acc[1], 0.f);
    s0.z = fmaxf(acc[2], 0.f); s0.w = fmaxf(acc[3], 0.f);
    s1.x = fmaxf(acc[4], 0.f); s1.y = fmaxf(acc[5], 0.f);
    s1.z = fmaxf(acc[6], 0.f); s1.w = fmaxf(acc[7], 0.f);
    *(float4*)op = s0;
    *(float4*)(op + 4) = s1;
}

extern "C" void kernel_launch(void* const* d_in, const int* in_sizes, int n_in,
                              void* d_out, int out_size, void* d_ws, size_t ws_size,
                              hipStream_t stream) {
    const float* h    = (const float*)d_in[0];
    const int* adj    = (const int*)d_in[1];
    const float* Ww   = (const float*)d_in[2];
    const float* Wb   = (const float*)d_in[3];
    const float* attw = (const float*)d_in[4];
    float* out = (float*)d_out;
    char* ws = (char*)d_ws;
    // workspace layout (5.0 MB total)
    float* Wh     = (float*)(ws);                       // 4 MB
    float* eL     = (float*)(ws + 4194304);             // 128 KB
    float* eR     = (float*)(ws + 4325376);             // 128 KB
    float* mBuf   = (float*)(ws + 4456448);             // 128 KB
    float* invBuf = (float*)(ws + 4587520);             // 128 KB
    unsigned long long* mask = (unsigned long long*)(ws + 4718592);  // 512 KB

    k1_wh<<<dim3(BB * NN / K1_ROWS), dim3(128), 0, stream>>>(h, Ww, Wb, attw, Wh, eL, eR);
    k_pack<<<dim3(NN), dim3(256), 0, stream>>>(adj, mask);
    k2a_stats<<<dim3(BB * NN), dim3(256), 0, stream>>>(adj, eL, eR, mBuf, invBuf);
    k2b_agg<<<dim3(NN / TI, BB), dim3(256), 0, stream>>>(Wh, eL, eR, mBuf, invBuf, mask, out);
}

// Round 3
// 172.472 us; speedup vs baseline: 2.1413x; 2.1413x over previous
//
#include <hip/hip_runtime.h>
#include <stdint.h>

#define BB 4
#define NN 2048
#define FIN 256
#define FOUT 128
#define NH 4
#define NEG_SLOPE 0.2f

typedef short bf16x8 __attribute__((ext_vector_type(8)));   // 8 bf16 = 4 VGPRs
typedef unsigned short u16x8 __attribute__((ext_vector_type(8)));
typedef float f32x4 __attribute__((ext_vector_type(4)));
typedef unsigned long long u64;

__device__ inline unsigned short f2b(float f) {   // fp32 -> bf16 RNE
    union { float f; unsigned int i; } x; x.f = f;
    unsigned int r = x.i + 0x7fffu + ((x.i >> 16) & 1u);
    return (unsigned short)(r >> 16);
}

// ---------------------------------------------------------------------------
// K1: Wh row = h row @ W^T + b (fp32 accum). Writes WhT[b][o][n] in bf16
//     (o-major so k2b B-fragments are contiguous in j), plus eL/eR fp32.
// ---------------------------------------------------------------------------
#define K1_ROWS 8
__global__ __launch_bounds__(128) void k1_wh(
    const float* __restrict__ h, const float* __restrict__ Ww,
    const float* __restrict__ Wb, const float* __restrict__ attw,
    unsigned short* __restrict__ WhT, float* __restrict__ eL, float* __restrict__ eR) {
    __shared__ float hs[K1_ROWS][FIN];        // 8 KB
    __shared__ float whs[K1_ROWS][FOUT + 4];
    int t = threadIdx.x;
    int b = blockIdx.x >> 8;
    int tile = blockIdx.x & 255;
    int n0 = tile * K1_ROWS;
    const float* hb = h + ((size_t)(b * NN + n0)) * FIN;
    #pragma unroll
    for (int k = 0; k < 4; ++k) {
        int flat = (t + 128 * k) * 4;
        int r = flat >> 8, f = flat & 255;
        *(float4*)&hs[r][f] = *(const float4*)(hb + flat);
    }
    __syncthreads();
    int o = t;
    float bias = Wb[o];
    float acc[K1_ROWS];
    #pragma unroll
    for (int r = 0; r < K1_ROWS; ++r) acc[r] = bias;
    const float* wrow = Ww + (size_t)o * FIN;
    for (int fc = 0; fc < FIN / 4; ++fc) {
        float4 wq = *(const float4*)(wrow + fc * 4);
        #pragma unroll
        for (int r = 0; r < K1_ROWS; ++r) {
            float4 hv = *(const float4*)(&hs[r][fc * 4]);
            acc[r] = fmaf(hv.x, wq.x, acc[r]);
            acc[r] = fmaf(hv.y, wq.y, acc[r]);
            acc[r] = fmaf(hv.z, wq.z, acc[r]);
            acc[r] = fmaf(hv.w, wq.w, acc[r]);
        }
    }
    u16x8 wv;
    #pragma unroll
    for (int r = 0; r < K1_ROWS; ++r) {
        wv[r] = f2b(acc[r]);
        whs[r][o] = acc[r];
    }
    *(u16x8*)(WhT + (size_t)(b * FOUT + o) * NN + n0) = wv;   // 16B store
    __syncthreads();
    if (t < 64) {
        int r = t >> 3, d = t & 7;
        int hh = d & 3, side = d >> 2;
        const float* arow = attw + hh * (2 * FOUT) + side * FOUT;
        float s = 0.f;
        for (int oo = 0; oo < FOUT; ++oo) s = fmaf(whs[r][oo], arow[oo], s);
        float* dst = side ? eR : eL;
        dst[(b * NH + hh) * NN + (n0 + r)] = s;
    }
}

// ---------------------------------------------------------------------------
// K_pack: adj (N x N int32) -> bitmask (N rows x 32 u64)
// ---------------------------------------------------------------------------
__global__ __launch_bounds__(256) void k_pack(const int* __restrict__ adj,
                                              u64* __restrict__ mask) {
    int row = blockIdx.x;
    int wave = threadIdx.x >> 6, lane = threadIdx.x & 63;
    #pragma unroll
    for (int it = 0; it < 8; ++it) {
        int w = it * 4 + wave;
        int j = w * 64 + lane;
        u64 m = __ballot(adj[(size_t)row * NN + j] != 0);
        if (lane == 0) mask[row * 32 + w] = m;
    }
}

// ---------------------------------------------------------------------------
// K2a: s[b,h,i] = sum_{j: adj_ij} exp(leaky(eL[b,h,i]+eR[b,h,j]))
//      inv = 1/(4s) (0 if empty). No max shift: |e| <~ 15 << 88, shift-invariant.
// Block = 256 thr, 16 i rows; eR staged in LDS (pad+rotate for banks).
// ---------------------------------------------------------------------------
__global__ __launch_bounds__(256) void k2a_stats(
    const float* __restrict__ eL, const float* __restrict__ eR,
    const u64* __restrict__ mask, float* __restrict__ invOut) {
    __shared__ float er_s[NH][2052];          // pad 4: (h,jq) spread 2-way max
    __shared__ u64 mw2[16][32];
    __shared__ float els2[NH][16];
    int t = threadIdx.x;
    int b = blockIdx.y, i0 = blockIdx.x * 16;
    const float* src = eR + (size_t)b * NH * NN;
    #pragma unroll
    for (int k = 0; k < 8; ++k) {
        int idx = (t + 256 * k) * 4;
        int hh = idx >> 11, jj = idx & 2047;
        *(float4*)&er_s[hh][jj] = *(const float4*)(src + idx);
    }
    #pragma unroll
    for (int k = 0; k < 2; ++k) {
        int idx = t + 256 * k; int r = idx >> 5, w = idx & 31;
        mw2[r][w] = mask[(size_t)(i0 + r) * 32 + w];
    }
    if (t < 64) {
        int hh = t >> 4, il = t & 15;
        els2[hh][il] = eL[((size_t)b * NH + hh) * NN + i0 + il];
    }
    __syncthreads();
    int il = t >> 4, sub = t & 15, hh = sub & 3, jq = sub >> 2;
    float el = els2[hh][il];
    int rot = 8 * jq;
    float s = 0.f;
    for (int wq = 0; wq < 8; ++wq) {
        u64 word = mw2[il][jq * 8 + wq];
        int base = jq * 512 + wq * 64;
        #pragma unroll 8
        for (int jj = 0; jj < 64; ++jj) {
            int jr = (jj + rot) & 63;
            float e = el + er_s[hh][base + jr];
            e = e > 0.f ? e : NEG_SLOPE * e;
            float p = __expf(e);
            s += ((word >> jr) & 1ull) ? p : 0.f;
        }
    }
    s += __shfl_xor(s, 4);
    s += __shfl_xor(s, 8);
    if (jq == 0)
        invOut[((size_t)b * NH + hh) * NN + i0 + il] = (s > 0.f) ? 1.f / (4.f * s) : 0.f;
}

// ---------------------------------------------------------------------------
// K2b: out[b,i,o] = relu( sum_j w[i,j] * Wh[b,j,o] ), MFMA 16x16x32 bf16.
//   w[i,j] = adj_ij ? sum_h exp(leaky(el+er))*inv_h : 0  (bf16 A-tile in LDS)
//   B = WhT[b][o][j] bf16 (contiguous j -> one 16B load per fragment).
// Block = 256 thr (4 waves), i-tile 16, o split 32 per wave; K-loop j by 256.
// ---------------------------------------------------------------------------
__global__ __launch_bounds__(256) void k2b_mfma(
    const unsigned short* __restrict__ WhT, const float* __restrict__ eL,
    const float* __restrict__ eR, const float* __restrict__ invIn,
    const u64* __restrict__ mask, float* __restrict__ out) {
    __shared__ unsigned short wt[16][264];    // bf16 A tile, pad 8 (16B) per row
    __shared__ float els[NH][16], invs[NH][16];
    __shared__ u64 mw[16][4];
    int t = threadIdx.x;
    int b = blockIdx.y, i0 = blockIdx.x * 16;
    if (t < 64) {
        int hh = t >> 4, il = t & 15;
        els[hh][il]  = eL[((size_t)b * NH + hh) * NN + i0 + il];
        invs[hh][il] = invIn[((size_t)b * NH + hh) * NN + i0 + il];
    }
    int lane = t & 63, wavei = t >> 6;
    int m = lane & 15, quad = lane >> 4;
    int o0 = wavei * 32;
    const unsigned short* bp0 = WhT + (size_t)(b * FOUT + o0 + m) * NN;
    const unsigned short* bp1 = WhT + (size_t)(b * FOUT + o0 + 16 + m) * NN;
    f32x4 acc0 = {0.f, 0.f, 0.f, 0.f}, acc1 = {0.f, 0.f, 0.f, 0.f};

    for (int jt = 0; jt < 8; ++jt) {
        int j0 = jt * 256;
        if (t < 64) {
            int r = t >> 2, wsel = t & 3;
            mw[r][wsel] = mask[(size_t)(i0 + r) * 32 + jt * 4 + wsel];
        }
        __syncthreads();   // mw staged; prev MFMA phase done reading wt
        {   // w-gen: thread == jl, computes 16 rows
            int jl = t;
            float er0 = eR[((size_t)b * NH + 0) * NN + j0 + jl];
            float er1 = eR[((size_t)b * NH + 1) * NN + j0 + jl];
            float er2 = eR[((size_t)b * NH + 2) * NN + j0 + jl];
            float er3 = eR[((size_t)b * NH + 3) * NN + j0 + jl];
            unsigned int sh = jl & 63;
            int wsel = jl >> 6;
            #pragma unroll 4
            for (int r = 0; r < 16; ++r) {
                u64 wd = mw[r][wsel];
                float e0 = els[0][r] + er0; e0 = e0 > 0.f ? e0 : NEG_SLOPE * e0;
                float e1 = els[1][r] + er1; e1 = e1 > 0.f ? e1 : NEG_SLOPE * e1;
                float e2 = els[2][r] + er2; e2 = e2 > 0.f ? e2 : NEG_SLOPE * e2;
                float e3 = els[3][r] + er3; e3 = e3 > 0.f ? e3 : NEG_SLOPE * e3;
                float p = __expf(e0) * invs[0][r];
                p = fmaf(__expf(e1), invs[1][r], p);
                p = fmaf(__expf(e2), invs[2][r], p);
                p = fmaf(__expf(e3), invs[3][r], p);
                wt[r][jl] = ((wd >> sh) & 1ull) ? f2b(p) : 0;
            }
        }
        __syncthreads();
        #pragma unroll
        for (int ks = 0; ks < 8; ++ks) {
            int ko = ks * 32 + quad * 8;
            bf16x8 a  = *(bf16x8*)&wt[m][ko];
            bf16x8 b0 = *(const bf16x8*)(bp0 + j0 + ko);
            bf16x8 b1 = *(const bf16x8*)(bp1 + j0 + ko);
            acc0 = __builtin_amdgcn_mfma_f32_16x16x32_bf16(a, b0, acc0, 0, 0, 0);
            acc1 = __builtin_amdgcn_mfma_f32_16x16x32_bf16(a, b1, acc1, 0, 0, 0);
        }
    }
    float* ob = out + ((size_t)b * NN + i0) * FOUT;
    #pragma unroll
    for (int reg = 0; reg < 4; ++reg) {
        int row = quad * 4 + reg;
        ob[(size_t)row * FOUT + o0 + m]      = fmaxf(acc0[reg], 0.f);
        ob[(size_t)row * FOUT + o0 + 16 + m] = fmaxf(acc1[reg], 0.f);
    }
}

extern "C" void kernel_launch(void* const* d_in, const int* in_sizes, int n_in,
                              void* d_out, int out_size, void* d_ws, size_t ws_size,
                              hipStream_t stream) {
    const float* h    = (const float*)d_in[0];
    const int* adj    = (const int*)d_in[1];
    const float* Ww   = (const float*)d_in[2];
    const float* Wb   = (const float*)d_in[3];
    const float* attw = (const float*)d_in[4];
    float* out = (float*)d_out;
    char* ws = (char*)d_ws;
    // workspace layout (3.0 MB)
    unsigned short* WhT = (unsigned short*)(ws);        // 2 MB  [b][o][j] bf16
    float* eL     = (float*)(ws + 2097152);             // 128 KB
    float* eR     = (float*)(ws + 2228224);             // 128 KB
    float* invBuf = (float*)(ws + 2359296);             // 128 KB
    u64*   mask   = (u64*)(ws + 2490368);               // 512 KB

    k1_wh<<<dim3(BB * NN / K1_ROWS), dim3(128), 0, stream>>>(h, Ww, Wb, attw, WhT, eL, eR);
    k_pack<<<dim3(NN), dim3(256), 0, stream>>>(adj, mask);
    k2a_stats<<<dim3(NN / 16, BB), dim3(256), 0, stream>>>(eL, eR, mask, invBuf);
    k2b_mfma<<<dim3(NN / 16, BB), dim3(256), 0, stream>>>(WhT, eL, eR, invBuf, mask, out);
}